// Round 2
// baseline (140.035 us; speedup 1.0000x reference)
//
#include <hip/hip_runtime.h>
#include <stdint.h>

// Problem constants (fixed shapes from reference)
#define M_ROWS 6272   // 32*196
#define K_DIM  768
#define N_DIM  3072
#define BM 128
#define BN 128
#define BK 32
#define NITER (K_DIM / BK)   // 24

#define X_CHUNKS (M_ROWS * K_DIM / 8)   // 602112
#define W_CHUNKS (N_DIM * K_DIM / 8)    // 294912
#define X_BLOCKS (X_CHUNKS / 256)       // 2352
#define W_BLOCKS (W_CHUNKS / 256)       // 1152

typedef unsigned short u16;
typedef __attribute__((ext_vector_type(8))) __bf16 bf16x8;
typedef __attribute__((ext_vector_type(4))) float f32x4;

__device__ __forceinline__ u16 f32_to_bf16(float f) {
    unsigned u = __float_as_uint(f);
    unsigned r = 0x7FFFu + ((u >> 16) & 1u);
    return (u16)((u + r) >> 16);
}

__device__ __forceinline__ unsigned pack2(float a, float b) {
    return (unsigned)f32_to_bf16(a) | ((unsigned)f32_to_bf16(b) << 16);
}

// Fused prep: blocks [0, X_BLOCKS) cast x fp32->bf16;
// blocks [X_BLOCKS, X_BLOCKS+W_BLOCKS) expand block-circulant W to bf16.
__global__ void prep_kernel(const float* __restrict__ x, const float* __restrict__ w,
                            u16* __restrict__ xb, u16* __restrict__ wb) {
    int b = blockIdx.x;
    if (b < X_BLOCKS) {
        int idx = b * 256 + threadIdx.x;
        const float4* xp = (const float4*)x + (size_t)idx * 2;
        float4 a = xp[0], c = xp[1];
        uint4 v;
        v.x = pack2(a.x, a.y);
        v.y = pack2(a.z, a.w);
        v.z = pack2(c.x, c.y);
        v.w = pack2(c.z, c.w);
        ((uint4*)xb)[idx] = v;
    } else {
        int idx = (b - X_BLOCKS) * 256 + threadIdx.x;
        int n    = idx / 96;          // output row [0,3072)
        int kc   = idx - n * 96;      // 8-elem chunk along K
        int kblk = n / 768;           // 0..3
        int o    = n - kblk * 768;    // 0..767
        int j    = kc / 24;           // 0..3
        int c8   = kc - j * 24;       // 0..23
        int i    = (kblk - j) & 3;    // (kblk - j) mod 4
        const float* src = w + (((size_t)i * 768 + o) * 192 + c8 * 8);
        float4 a = ((const float4*)src)[0];
        float4 c = ((const float4*)src)[1];
        uint4 v;
        v.x = pack2(a.x, a.y);
        v.y = pack2(a.z, a.w);
        v.z = pack2(c.x, c.y);
        v.w = pack2(c.z, c.w);
        ((uint4*)wb)[idx] = v;
    }
}

__device__ __forceinline__ void load_lds16(const u16* g, u16* l) {
    __builtin_amdgcn_global_load_lds(
        (const __attribute__((address_space(1))) void*)g,
        (__attribute__((address_space(3))) void*)l, 16, 0, 0);
}

// C[m,n] = sum_k A[m,k]*B[n,k] + bias[n]; A,B bf16 row-major K-contig, C fp32.
// LDS layout is XOR-swizzled: 16B chunk for (row r, k-slot s) lives at LDS slot
// s ^ ((r>>1)&3) within row r. Swizzle is applied on the GLOBAL source index in
// staging (global_load_lds demands contiguous lane->LDS mapping) and mirrored
// on the ds_read side. Makes every 8-lane phase of ds_read_b128 hit all 32
// banks exactly once (was 4-way aliased -> 3.6M conflict cycles in R1).
__global__ __launch_bounds__(256) void gemm_bt(
    const u16* __restrict__ A,    // [M_ROWS, K_DIM] bf16
    const u16* __restrict__ B,    // [N_DIM,  K_DIM] bf16
    const float* __restrict__ bias,
    float* __restrict__ C)
{
    // double-buffered: 2 x (8KB + 8KB) = 32 KB
    __shared__ u16 As[2][BM * BK];
    __shared__ u16 Bs[2][BN * BK];

    const int tid    = threadIdx.x;
    const int wave   = tid >> 6;
    const int lane   = tid & 63;
    const int lane16 = lane & 15;
    const int quad   = lane >> 4;
    const int wr     = wave >> 1;   // wave row (0..1) -> 64 rows each
    const int wc     = wave & 1;    // wave col (0..1) -> 64 cols each

    const int rowBase = blockIdx.y * BM;
    const int colBase = blockIdx.x * BN;

    // staging: chunk c in [0,512): row = c>>2, lds slot = c&3, global k-slot
    // = (c&3) ^ swz(row). 16B per chunk.
    const int c0 = tid;
    const int c1 = tid + 256;
    const int r0 = c0 >> 2, s0 = (c0 & 3) ^ ((r0 >> 1) & 3);
    const int r1 = c1 >> 2, s1 = (c1 & 3) ^ ((r1 >> 1) & 3);
    const u16* Ag0 = A + (size_t)(rowBase + r0) * K_DIM + s0 * 8;
    const u16* Ag1 = A + (size_t)(rowBase + r1) * K_DIM + s1 * 8;
    const u16* Bg0 = B + (size_t)(colBase + r0) * K_DIM + s0 * 8;
    const u16* Bg1 = B + (size_t)(colBase + r1) * K_DIM + s1 * 8;
    const int l0 = c0 * 8;   // lds element offset of chunk
    const int l1 = c1 * 8;

    // read-side swizzle: for fragment row r = (mult of 16) + lane16, k-slot q:
    // lds slot = q ^ ((r>>1)&3) = q ^ ((lane16>>1)&3)  (base is mult of 16)
    const int swz  = (lane16 >> 1) & 3;
    const int slot = (quad ^ swz) * 8;          // element offset within row
    int aoff[4], boff[4];
#pragma unroll
    for (int i = 0; i < 4; ++i)
        aoff[i] = (wr * 64 + i * 16 + lane16) * BK + slot;
#pragma unroll
    for (int j = 0; j < 4; ++j)
        boff[j] = (wc * 64 + j * 16 + lane16) * BK + slot;

    f32x4 acc[4][4] = {};

    // prologue: stage tile 0 into buffer 0
    load_lds16(Ag0, &As[0][l0]);
    load_lds16(Ag1, &As[0][l1]);
    load_lds16(Bg0, &Bs[0][l0]);
    load_lds16(Bg1, &Bs[0][l1]);

#pragma unroll 2
    for (int it = 0; it < NITER; ++it) {
        const int cur = it & 1, nxt = cur ^ 1;
        __syncthreads();   // drains vmcnt -> buf[cur] ready; lgkm -> buf[nxt] readers done
        if (it + 1 < NITER) {
            const int k = (it + 1) * BK;
            load_lds16(Ag0 + k, &As[nxt][l0]);
            load_lds16(Ag1 + k, &As[nxt][l1]);
            load_lds16(Bg0 + k, &Bs[nxt][l0]);
            load_lds16(Bg1 + k, &Bs[nxt][l1]);
        }

        bf16x8 af[4], bfv[4];
#pragma unroll
        for (int i = 0; i < 4; ++i)
            af[i] = *(const bf16x8*)&As[cur][aoff[i]];
#pragma unroll
        for (int j = 0; j < 4; ++j)
            bfv[j] = *(const bf16x8*)&Bs[cur][boff[j]];
#pragma unroll
        for (int i = 0; i < 4; ++i)
#pragma unroll
            for (int j = 0; j < 4; ++j)
                acc[i][j] = __builtin_amdgcn_mfma_f32_16x16x32_bf16(
                    af[i], bfv[j], acc[i][j], 0, 0, 0);
    }

    // epilogue: C[row][col] = acc + bias[col]
    float bv[4];
#pragma unroll
    for (int j = 0; j < 4; ++j)
        bv[j] = bias[colBase + wc * 64 + j * 16 + lane16];
#pragma unroll
    for (int i = 0; i < 4; ++i) {
        int row0 = rowBase + wr * 64 + i * 16 + quad * 4;
#pragma unroll
        for (int r = 0; r < 4; ++r) {
            float* cp = C + (size_t)(row0 + r) * N_DIM + colBase + wc * 64 + lane16;
#pragma unroll
            for (int j = 0; j < 4; ++j)
                cp[j * 16] = acc[i][j][r] + bv[j];
        }
    }
}

extern "C" void kernel_launch(void* const* d_in, const int* in_sizes, int n_in,
                              void* d_out, int out_size, void* d_ws, size_t ws_size,
                              hipStream_t stream) {
    const float* x    = (const float*)d_in[0];
    const float* w    = (const float*)d_in[1];
    const float* bias = (const float*)d_in[2];
    float* out = (float*)d_out;

    u16* xb = (u16*)d_ws;                                       // 9,633,792 B
    u16* wb = (u16*)((char*)d_ws + (size_t)M_ROWS * K_DIM * 2); // +4,718,592 B

    hipLaunchKernelGGL(prep_kernel, dim3(X_BLOCKS + W_BLOCKS), dim3(256),
                       0, stream, x, w, xb, wb);
    hipLaunchKernelGGL(gemm_bt, dim3(N_DIM / BN, M_ROWS / BM), dim3(256),
                       0, stream, xb, wb, bias, out);
}

// Round 3
// 134.916 us; speedup vs baseline: 1.0379x; 1.0379x over previous
//
#include <hip/hip_runtime.h>
#include <stdint.h>

// Problem constants (fixed shapes from reference)
#define M_ROWS 6272   // 32*196
#define K_DIM  768
#define N_DIM  3072
#define BM 128
#define BN 128
#define BK 32
#define NITER (K_DIM / BK)   // 24

#define X_CHUNKS (M_ROWS * K_DIM / 8)   // 602112
#define W_CHUNKS (N_DIM * K_DIM / 8)    // 294912
#define X_BLOCKS (X_CHUNKS / 256)       // 2352
#define W_BLOCKS (W_CHUNKS / 256)       // 1152

typedef unsigned short u16;
typedef __attribute__((ext_vector_type(8))) __bf16 bf16x8;
typedef __attribute__((ext_vector_type(4))) float f32x4;

__device__ __forceinline__ u16 f32_to_bf16(float f) {
    unsigned u = __float_as_uint(f);
    unsigned r = 0x7FFFu + ((u >> 16) & 1u);
    return (u16)((u + r) >> 16);
}

__device__ __forceinline__ unsigned pack2(float a, float b) {
    return (unsigned)f32_to_bf16(a) | ((unsigned)f32_to_bf16(b) << 16);
}

// Fused prep: blocks [0, X_BLOCKS) cast x fp32->bf16;
// blocks [X_BLOCKS, X_BLOCKS+W_BLOCKS) expand block-circulant W to bf16.
__global__ void prep_kernel(const float* __restrict__ x, const float* __restrict__ w,
                            u16* __restrict__ xb, u16* __restrict__ wb) {
    int b = blockIdx.x;
    if (b < X_BLOCKS) {
        int idx = b * 256 + threadIdx.x;
        const float4* xp = (const float4*)x + (size_t)idx * 2;
        float4 a = xp[0], c = xp[1];
        uint4 v;
        v.x = pack2(a.x, a.y);
        v.y = pack2(a.z, a.w);
        v.z = pack2(c.x, c.y);
        v.w = pack2(c.z, c.w);
        ((uint4*)xb)[idx] = v;
    } else {
        int idx = (b - X_BLOCKS) * 256 + threadIdx.x;
        int n    = idx / 96;          // output row [0,3072)
        int kc   = idx - n * 96;      // 8-elem chunk along K
        int kblk = n / 768;           // 0..3
        int o    = n - kblk * 768;    // 0..767
        int j    = kc / 24;           // 0..3
        int c8   = kc - j * 24;       // 0..23
        int i    = (kblk - j) & 3;    // (kblk - j) mod 4
        const float* src = w + (((size_t)i * 768 + o) * 192 + c8 * 8);
        float4 a = ((const float4*)src)[0];
        float4 c = ((const float4*)src)[1];
        uint4 v;
        v.x = pack2(a.x, a.y);
        v.y = pack2(a.z, a.w);
        v.z = pack2(c.x, c.y);
        v.w = pack2(c.z, c.w);
        ((uint4*)wb)[idx] = v;
    }
}

// C[m,n] = sum_k A[m,k]*B[n,k] + bias[n]; A,B bf16 row-major K-contig, C fp32.
//
// Pipeline (register-staged, NOT global_load_lds): per iter, each thread holds
// the NEXT tile's 4x16B chunks in VGPRs (loaded one full iteration earlier),
// ds_writes them into the alternate LDS buffer after the MFMA phase, then
// issues loads for tile it+2. The barrier's drain is lgkmcnt-only (ds_write,
// ~30 cyc) — global-load latency is hidden across a whole iteration instead
// of being welded to the barrier by global_load_lds's vmcnt(0) drain (the R1/R2
// structural stall).
//
// LDS XOR swizzle (R2, verified, conflicts=0): 16B chunk for (row r, k-slot s)
// lives at slot s ^ ((r>>1)&3); applied on the GLOBAL source k-offset during
// staging, mirrored on the ds_read side.
__global__ __launch_bounds__(256) void gemm_bt(
    const u16* __restrict__ A,    // [M_ROWS, K_DIM] bf16
    const u16* __restrict__ B,    // [N_DIM,  K_DIM] bf16
    const float* __restrict__ bias,
    float* __restrict__ C)
{
    __shared__ u16 As[2][BM * BK];   // 2 x 8 KB
    __shared__ u16 Bs[2][BN * BK];   // 2 x 8 KB

    const int tid    = threadIdx.x;
    const int wave   = tid >> 6;
    const int lane   = tid & 63;
    const int lane16 = lane & 15;
    const int quad   = lane >> 4;
    const int wr     = wave >> 1;   // wave row (0..1) -> 64 rows each
    const int wc     = wave & 1;    // wave col (0..1) -> 64 cols each

    const int rowBase = blockIdx.y * BM;
    const int colBase = blockIdx.x * BN;

    // staging: chunk c in [0,512): row = c>>2, lds slot = c&3,
    // global k-slot = (c&3) ^ ((row>>1)&3). 16B per chunk; 2 A + 2 B per thread.
    const int c0 = tid;
    const int c1 = tid + 256;
    const int r0 = c0 >> 2, s0 = (c0 & 3) ^ ((r0 >> 1) & 3);
    const int r1 = c1 >> 2, s1 = (c1 & 3) ^ ((r1 >> 1) & 3);
    const uint4* Ag0 = (const uint4*)(A + (size_t)(rowBase + r0) * K_DIM + s0 * 8);
    const uint4* Ag1 = (const uint4*)(A + (size_t)(rowBase + r1) * K_DIM + s1 * 8);
    const uint4* Bg0 = (const uint4*)(B + (size_t)(colBase + r0) * K_DIM + s0 * 8);
    const uint4* Bg1 = (const uint4*)(B + (size_t)(colBase + r1) * K_DIM + s1 * 8);
    // BK elements per row step of 16B-chunks: advancing one K-tile = BK*2 bytes = 4 uint4
    uint4* Al0 = (uint4*)&As[0][c0 * 8];   // same element offset in either buffer
    uint4* Al1 = (uint4*)&As[0][c1 * 8];
    uint4* Bl0 = (uint4*)&Bs[0][c0 * 8];
    uint4* Bl1 = (uint4*)&Bs[0][c1 * 8];
    const int bufStride = (BM * BK) / 8;   // uint4 elements per LDS buffer

    // read-side swizzle
    const int swz  = (lane16 >> 1) & 3;
    const int slot = (quad ^ swz) * 8;
    int aoff[4], boff[4];
#pragma unroll
    for (int i = 0; i < 4; ++i)
        aoff[i] = (wr * 64 + i * 16 + lane16) * BK + slot;
#pragma unroll
    for (int j = 0; j < 4; ++j)
        boff[j] = (wc * 64 + j * 16 + lane16) * BK + slot;

    f32x4 acc[4][4] = {};

    // K-step in uint4 units: one K-tile advance = BK/8 uint4 per row
    const int kStep = BK / 8;   // 4

    // prologue: tile0 -> regs -> LDS buf0; tile1 -> regs
    uint4 ga0 = Ag0[0], ga1 = Ag1[0], gb0 = Bg0[0], gb1 = Bg1[0];
    Al0[0] = ga0; Al1[0] = ga1; Bl0[0] = gb0; Bl1[0] = gb1;
    ga0 = Ag0[kStep]; ga1 = Ag1[kStep]; gb0 = Bg0[kStep]; gb1 = Bg1[kStep];
    __syncthreads();

#pragma unroll 2
    for (int it = 0; it < NITER - 2; ++it) {
        const int cur = it & 1, nxt = cur ^ 1;

        bf16x8 af[4], bfv[4];
#pragma unroll
        for (int i = 0; i < 4; ++i)
            af[i] = *(const bf16x8*)&As[cur][aoff[i]];
#pragma unroll
        for (int j = 0; j < 4; ++j)
            bfv[j] = *(const bf16x8*)&Bs[cur][boff[j]];
#pragma unroll
        for (int i = 0; i < 4; ++i)
#pragma unroll
            for (int j = 0; j < 4; ++j)
                acc[i][j] = __builtin_amdgcn_mfma_f32_16x16x32_bf16(
                    af[i], bfv[j], acc[i][j], 0, 0, 0);

        // stage tile it+1 (already in regs) into buf[nxt]
        const int o = nxt * bufStride;
        Al0[o] = ga0; Al1[o] = ga1; Bl0[o] = gb0; Bl1[o] = gb1;
        // issue loads for tile it+2
        const int g = (it + 2) * kStep;
        ga0 = Ag0[g]; ga1 = Ag1[g]; gb0 = Bg0[g]; gb1 = Bg1[g];
        __syncthreads();
    }

    // it = NITER-2: compute, stage last tile, no more loads
    {
        const int cur = (NITER - 2) & 1, nxt = cur ^ 1;
        bf16x8 af[4], bfv[4];
#pragma unroll
        for (int i = 0; i < 4; ++i)
            af[i] = *(const bf16x8*)&As[cur][aoff[i]];
#pragma unroll
        for (int j = 0; j < 4; ++j)
            bfv[j] = *(const bf16x8*)&Bs[cur][boff[j]];
#pragma unroll
        for (int i = 0; i < 4; ++i)
#pragma unroll
            for (int j = 0; j < 4; ++j)
                acc[i][j] = __builtin_amdgcn_mfma_f32_16x16x32_bf16(
                    af[i], bfv[j], acc[i][j], 0, 0, 0);
        const int o = nxt * bufStride;
        Al0[o] = ga0; Al1[o] = ga1; Bl0[o] = gb0; Bl1[o] = gb1;
        __syncthreads();
    }

    // it = NITER-1: compute only
    {
        const int cur = (NITER - 1) & 1;
        bf16x8 af[4], bfv[4];
#pragma unroll
        for (int i = 0; i < 4; ++i)
            af[i] = *(const bf16x8*)&As[cur][aoff[i]];
#pragma unroll
        for (int j = 0; j < 4; ++j)
            bfv[j] = *(const bf16x8*)&Bs[cur][boff[j]];
#pragma unroll
        for (int i = 0; i < 4; ++i)
#pragma unroll
            for (int j = 0; j < 4; ++j)
                acc[i][j] = __builtin_amdgcn_mfma_f32_16x16x32_bf16(
                    af[i], bfv[j], acc[i][j], 0, 0, 0);
    }

    // epilogue: C[row][col] = acc + bias[col]
    float bv[4];
#pragma unroll
    for (int j = 0; j < 4; ++j)
        bv[j] = bias[colBase + wc * 64 + j * 16 + lane16];
#pragma unroll
    for (int i = 0; i < 4; ++i) {
        int row0 = rowBase + wr * 64 + i * 16 + quad * 4;
#pragma unroll
        for (int r = 0; r < 4; ++r) {
            float* cp = C + (size_t)(row0 + r) * N_DIM + colBase + wc * 64 + lane16;
#pragma unroll
            for (int j = 0; j < 4; ++j)
                cp[j * 16] = acc[i][j][r] + bv[j];
        }
    }
}

extern "C" void kernel_launch(void* const* d_in, const int* in_sizes, int n_in,
                              void* d_out, int out_size, void* d_ws, size_t ws_size,
                              hipStream_t stream) {
    const float* x    = (const float*)d_in[0];
    const float* w    = (const float*)d_in[1];
    const float* bias = (const float*)d_in[2];
    float* out = (float*)d_out;

    u16* xb = (u16*)d_ws;                                       // 9,633,792 B
    u16* wb = (u16*)((char*)d_ws + (size_t)M_ROWS * K_DIM * 2); // +4,718,592 B

    hipLaunchKernelGGL(prep_kernel, dim3(X_BLOCKS + W_BLOCKS), dim3(256),
                       0, stream, x, w, xb, wb);
    hipLaunchKernelGGL(gemm_bt, dim3(N_DIM / BN, M_ROWS / BM), dim3(256),
                       0, stream, xb, wb, bias, out);
}

// Round 4
// 134.447 us; speedup vs baseline: 1.0416x; 1.0035x over previous
//
#include <hip/hip_runtime.h>
#include <stdint.h>

// Problem constants (fixed shapes from reference)
#define M_ROWS 6272   // 32*196
#define K_DIM  768
#define N_DIM  3072
#define BM 128
#define BN 128
#define BK 32
#define NITER (K_DIM / BK)   // 24

#define X_CHUNKS (M_ROWS * K_DIM / 8)   // 602112
#define W_CHUNKS (N_DIM * K_DIM / 8)    // 294912
#define X_BLOCKS (X_CHUNKS / 256)       // 2352
#define W_BLOCKS (W_CHUNKS / 256)       // 1152

typedef unsigned short u16;
typedef __attribute__((ext_vector_type(8))) __bf16 bf16x8;
typedef __attribute__((ext_vector_type(4))) float f32x4;

__device__ __forceinline__ u16 f32_to_bf16(float f) {
    unsigned u = __float_as_uint(f);
    unsigned r = 0x7FFFu + ((u >> 16) & 1u);
    return (u16)((u + r) >> 16);
}

__device__ __forceinline__ unsigned pack2(float a, float b) {
    return (unsigned)f32_to_bf16(a) | ((unsigned)f32_to_bf16(b) << 16);
}

// LDS-only barrier: drains lgkmcnt (ds ops) but deliberately NOT vmcnt, so
// prefetched global loads stay in flight across the barrier. HIP's
// __syncthreads() always emits s_waitcnt vmcnt(0) before s_barrier, which
// welds global-load latency to every K-iteration (the R1-R3 50-63us plateau).
// "memory" clobber stops the compiler caching/reordering LDS accesses across it.
__device__ __forceinline__ void lds_barrier() {
    asm volatile("s_waitcnt lgkmcnt(0)\n\ts_barrier" ::: "memory");
}

// Fused prep: blocks [0, X_BLOCKS) cast x fp32->bf16;
// blocks [X_BLOCKS, X_BLOCKS+W_BLOCKS) expand block-circulant W to bf16.
__global__ void prep_kernel(const float* __restrict__ x, const float* __restrict__ w,
                            u16* __restrict__ xb, u16* __restrict__ wb) {
    int b = blockIdx.x;
    if (b < X_BLOCKS) {
        int idx = b * 256 + threadIdx.x;
        const float4* xp = (const float4*)x + (size_t)idx * 2;
        float4 a = xp[0], c = xp[1];
        uint4 v;
        v.x = pack2(a.x, a.y);
        v.y = pack2(a.z, a.w);
        v.z = pack2(c.x, c.y);
        v.w = pack2(c.z, c.w);
        ((uint4*)xb)[idx] = v;
    } else {
        int idx = (b - X_BLOCKS) * 256 + threadIdx.x;
        int n    = idx / 96;          // output row [0,3072)
        int kc   = idx - n * 96;      // 8-elem chunk along K
        int kblk = n / 768;           // 0..3
        int o    = n - kblk * 768;    // 0..767
        int j    = kc / 24;           // 0..3
        int c8   = kc - j * 24;       // 0..23
        int i    = (kblk - j) & 3;    // (kblk - j) mod 4
        const float* src = w + (((size_t)i * 768 + o) * 192 + c8 * 8);
        float4 a = ((const float4*)src)[0];
        float4 c = ((const float4*)src)[1];
        uint4 v;
        v.x = pack2(a.x, a.y);
        v.y = pack2(a.z, a.w);
        v.z = pack2(c.x, c.y);
        v.w = pack2(c.z, c.w);
        ((uint4*)wb)[idx] = v;
    }
}

// C[m,n] = sum_k A[m,k]*B[n,k] + bias[n]; A,B bf16 row-major K-contig, C fp32.
//
// Register-staged pipeline: per iter each thread holds the NEXT tile's 4x16B
// chunks in VGPRs (loaded one full iteration earlier), ds_writes them into the
// alternate LDS buffer after the MFMA phase, then issues loads for tile it+2.
// Barriers are lgkm-only (lds_barrier) so those loads ride across iterations.
//
// LDS XOR swizzle (R2, verified, conflicts=0): 16B chunk for (row r, k-slot s)
// lives at slot s ^ ((r>>1)&3); applied on the GLOBAL source k-offset during
// staging, mirrored on the ds_read side.
__global__ __launch_bounds__(256) void gemm_bt(
    const u16* __restrict__ A,    // [M_ROWS, K_DIM] bf16
    const u16* __restrict__ B,    // [N_DIM,  K_DIM] bf16
    const float* __restrict__ bias,
    float* __restrict__ C)
{
    __shared__ u16 As[2][BM * BK];   // 2 x 8 KB
    __shared__ u16 Bs[2][BN * BK];   // 2 x 8 KB

    const int tid    = threadIdx.x;
    const int wave   = tid >> 6;
    const int lane   = tid & 63;
    const int lane16 = lane & 15;
    const int quad   = lane >> 4;
    const int wr     = wave >> 1;   // wave row (0..1) -> 64 rows each
    const int wc     = wave & 1;    // wave col (0..1) -> 64 cols each

    const int rowBase = blockIdx.y * BM;
    const int colBase = blockIdx.x * BN;

    // staging: chunk c in [0,512): row = c>>2, lds slot = c&3,
    // global k-slot = (c&3) ^ ((row>>1)&3). 16B per chunk; 2 A + 2 B per thread.
    const int c0 = tid;
    const int c1 = tid + 256;
    const int r0 = c0 >> 2, s0 = (c0 & 3) ^ ((r0 >> 1) & 3);
    const int r1 = c1 >> 2, s1 = (c1 & 3) ^ ((r1 >> 1) & 3);
    const uint4* Ag0 = (const uint4*)(A + (size_t)(rowBase + r0) * K_DIM + s0 * 8);
    const uint4* Ag1 = (const uint4*)(A + (size_t)(rowBase + r1) * K_DIM + s1 * 8);
    const uint4* Bg0 = (const uint4*)(B + (size_t)(colBase + r0) * K_DIM + s0 * 8);
    const uint4* Bg1 = (const uint4*)(B + (size_t)(colBase + r1) * K_DIM + s1 * 8);
    uint4* Al0 = (uint4*)&As[0][c0 * 8];   // same element offset in either buffer
    uint4* Al1 = (uint4*)&As[0][c1 * 8];
    uint4* Bl0 = (uint4*)&Bs[0][c0 * 8];
    uint4* Bl1 = (uint4*)&Bs[0][c1 * 8];
    const int bufStride = (BM * BK) / 8;   // uint4 elements per LDS buffer

    // read-side swizzle
    const int swz  = (lane16 >> 1) & 3;
    const int slot = (quad ^ swz) * 8;
    int aoff[4], boff[4];
#pragma unroll
    for (int i = 0; i < 4; ++i)
        aoff[i] = (wr * 64 + i * 16 + lane16) * BK + slot;
#pragma unroll
    for (int j = 0; j < 4; ++j)
        boff[j] = (wc * 64 + j * 16 + lane16) * BK + slot;

    f32x4 acc[4][4] = {};

    // K-step in uint4 units: one K-tile advance = BK/8 uint4 per row
    const int kStep = BK / 8;   // 4

    // prologue: tile0 -> regs -> LDS buf0; tile1 -> regs
    uint4 ga0 = Ag0[0], ga1 = Ag1[0], gb0 = Bg0[0], gb1 = Bg1[0];
    Al0[0] = ga0; Al1[0] = ga1; Bl0[0] = gb0; Bl1[0] = gb1;
    ga0 = Ag0[kStep]; ga1 = Ag1[kStep]; gb0 = Bg0[kStep]; gb1 = Bg1[kStep];
    lds_barrier();

#pragma unroll 2
    for (int it = 0; it < NITER - 2; ++it) {
        const int cur = it & 1, nxt = cur ^ 1;

        bf16x8 af[4], bfv[4];
#pragma unroll
        for (int i = 0; i < 4; ++i)
            af[i] = *(const bf16x8*)&As[cur][aoff[i]];
#pragma unroll
        for (int j = 0; j < 4; ++j)
            bfv[j] = *(const bf16x8*)&Bs[cur][boff[j]];
#pragma unroll
        for (int i = 0; i < 4; ++i)
#pragma unroll
            for (int j = 0; j < 4; ++j)
                acc[i][j] = __builtin_amdgcn_mfma_f32_16x16x32_bf16(
                    af[i], bfv[j], acc[i][j], 0, 0, 0);

        // stage tile it+1 (already in regs) into buf[nxt]
        const int o = nxt * bufStride;
        Al0[o] = ga0; Al1[o] = ga1; Bl0[o] = gb0; Bl1[o] = gb1;
        // issue loads for tile it+2
        const int g = (it + 2) * kStep;
        ga0 = Ag0[g]; ga1 = Ag1[g]; gb0 = Bg0[g]; gb1 = Bg1[g];
        lds_barrier();
    }

    // it = NITER-2: compute, stage last tile, no more loads
    {
        const int cur = (NITER - 2) & 1, nxt = cur ^ 1;
        bf16x8 af[4], bfv[4];
#pragma unroll
        for (int i = 0; i < 4; ++i)
            af[i] = *(const bf16x8*)&As[cur][aoff[i]];
#pragma unroll
        for (int j = 0; j < 4; ++j)
            bfv[j] = *(const bf16x8*)&Bs[cur][boff[j]];
#pragma unroll
        for (int i = 0; i < 4; ++i)
#pragma unroll
            for (int j = 0; j < 4; ++j)
                acc[i][j] = __builtin_amdgcn_mfma_f32_16x16x32_bf16(
                    af[i], bfv[j], acc[i][j], 0, 0, 0);
        const int o = nxt * bufStride;
        Al0[o] = ga0; Al1[o] = ga1; Bl0[o] = gb0; Bl1[o] = gb1;
        lds_barrier();
    }

    // it = NITER-1: compute only
    {
        const int cur = (NITER - 1) & 1;
        bf16x8 af[4], bfv[4];
#pragma unroll
        for (int i = 0; i < 4; ++i)
            af[i] = *(const bf16x8*)&As[cur][aoff[i]];
#pragma unroll
        for (int j = 0; j < 4; ++j)
            bfv[j] = *(const bf16x8*)&Bs[cur][boff[j]];
#pragma unroll
        for (int i = 0; i < 4; ++i)
#pragma unroll
            for (int j = 0; j < 4; ++j)
                acc[i][j] = __builtin_amdgcn_mfma_f32_16x16x32_bf16(
                    af[i], bfv[j], acc[i][j], 0, 0, 0);
    }

    // epilogue: C[row][col] = acc + bias[col]
    float bv[4];
#pragma unroll
    for (int j = 0; j < 4; ++j)
        bv[j] = bias[colBase + wc * 64 + j * 16 + lane16];
#pragma unroll
    for (int i = 0; i < 4; ++i) {
        int row0 = rowBase + wr * 64 + i * 16 + quad * 4;
#pragma unroll
        for (int r = 0; r < 4; ++r) {
            float* cp = C + (size_t)(row0 + r) * N_DIM + colBase + wc * 64 + lane16;
#pragma unroll
            for (int j = 0; j < 4; ++j)
                cp[j * 16] = acc[i][j][r] + bv[j];
        }
    }
}

extern "C" void kernel_launch(void* const* d_in, const int* in_sizes, int n_in,
                              void* d_out, int out_size, void* d_ws, size_t ws_size,
                              hipStream_t stream) {
    const float* x    = (const float*)d_in[0];
    const float* w    = (const float*)d_in[1];
    const float* bias = (const float*)d_in[2];
    float* out = (float*)d_out;

    u16* xb = (u16*)d_ws;                                       // 9,633,792 B
    u16* wb = (u16*)((char*)d_ws + (size_t)M_ROWS * K_DIM * 2); // +4,718,592 B

    hipLaunchKernelGGL(prep_kernel, dim3(X_BLOCKS + W_BLOCKS), dim3(256),
                       0, stream, x, w, xb, wb);
    hipLaunchKernelGGL(gemm_bt, dim3(N_DIM / BN, M_ROWS / BM), dim3(256),
                       0, stream, xb, wb, bias, out);
}